// Round 3
// baseline (113.852 us; speedup 1.0000x reference)
//
#include <hip/hip_runtime.h>

// Thresholded MSE == plain MSE (all branches compute (x-y)^2).
// Single fused kernel, last-block-done reduction:
//   - grid-stride float4 loads, unrolled x4, independent accumulators
//   - per-block deterministic partial -> d_ws
//   - __threadfence + atomic counter; last arriving block reduces the
//     2048 partials in a FIXED order (bit-deterministic) and writes mean.
// Counter zeroed each call via 4-byte hipMemsetAsync (graph-capturable).

#define BLOCKS 2048
#define THREADS 256

__global__ __launch_bounds__(THREADS) void mse_fused_kernel(
    const float* __restrict__ pred, const float* __restrict__ lab,
    float* __restrict__ partials, unsigned int* __restrict__ counter,
    float* __restrict__ out, int n_vec /* = N/4 */, float inv_n) {
    int tid = blockIdx.x * blockDim.x + threadIdx.x;
    int stride = gridDim.x * blockDim.x;

    const float4* p4 = reinterpret_cast<const float4*>(pred);
    const float4* l4 = reinterpret_cast<const float4*>(lab);

    float acc0 = 0.0f, acc1 = 0.0f, acc2 = 0.0f, acc3 = 0.0f;

    int i = tid;
    for (; i + 3 * stride < n_vec; i += 4 * stride) {
        float4 p0 = p4[i];
        float4 l0 = l4[i];
        float4 p1 = p4[i + stride];
        float4 l1 = l4[i + stride];
        float4 p2 = p4[i + 2 * stride];
        float4 l2 = l4[i + 2 * stride];
        float4 p3 = p4[i + 3 * stride];
        float4 l3 = l4[i + 3 * stride];

        float a0 = p0.x - l0.x, b0 = p0.y - l0.y, c0 = p0.z - l0.z, d0 = p0.w - l0.w;
        acc0 += a0 * a0 + b0 * b0 + c0 * c0 + d0 * d0;
        float a1 = p1.x - l1.x, b1 = p1.y - l1.y, c1 = p1.z - l1.z, d1 = p1.w - l1.w;
        acc1 += a1 * a1 + b1 * b1 + c1 * c1 + d1 * d1;
        float a2 = p2.x - l2.x, b2 = p2.y - l2.y, c2 = p2.z - l2.z, d2 = p2.w - l2.w;
        acc2 += a2 * a2 + b2 * b2 + c2 * c2 + d2 * d2;
        float a3 = p3.x - l3.x, b3 = p3.y - l3.y, c3 = p3.z - l3.z, d3 = p3.w - l3.w;
        acc3 += a3 * a3 + b3 * b3 + c3 * c3 + d3 * d3;
    }
    for (; i < n_vec; i += stride) {
        float4 p = p4[i];
        float4 l = l4[i];
        float a = p.x - l.x, b = p.y - l.y, c = p.z - l.z, d = p.w - l.w;
        acc0 += a * a + b * b + c * c + d * d;
    }

    float acc = (acc0 + acc1) + (acc2 + acc3);

    // wave64 reduce
    #pragma unroll
    for (int off = 32; off > 0; off >>= 1)
        acc += __shfl_down(acc, off, 64);

    __shared__ float wsum[THREADS / 64];
    __shared__ bool amLast;
    int lane = threadIdx.x & 63;
    int wave = threadIdx.x >> 6;
    if (lane == 0) wsum[wave] = acc;
    __syncthreads();
    if (threadIdx.x == 0) {
        float v = wsum[0] + wsum[1] + wsum[2] + wsum[3];
        partials[blockIdx.x] = v;
        __threadfence();  // make partial visible device-wide before signaling
        unsigned int old = atomicAdd(counter, 1u);
        amLast = (old == (unsigned int)(gridDim.x - 1));
    }
    __syncthreads();

    if (amLast) {
        __threadfence();  // acquire: see all blocks' partials
        float facc = 0.0f;
        for (int j = threadIdx.x; j < BLOCKS; j += THREADS)
            facc += partials[j];  // fixed order -> deterministic

        #pragma unroll
        for (int off = 32; off > 0; off >>= 1)
            facc += __shfl_down(facc, off, 64);

        if (lane == 0) wsum[wave] = facc;
        __syncthreads();
        if (threadIdx.x == 0) {
            float v = wsum[0] + wsum[1] + wsum[2] + wsum[3];
            out[0] = v * inv_n;
        }
    }
}

extern "C" void kernel_launch(void* const* d_in, const int* in_sizes, int n_in,
                              void* d_out, int out_size, void* d_ws, size_t ws_size,
                              hipStream_t stream) {
    const float* pred = (const float*)d_in[0];
    const float* lab  = (const float*)d_in[1];
    float* out = (float*)d_out;
    float* partials = (float*)d_ws;                       // BLOCKS floats
    unsigned int* counter = (unsigned int*)((char*)d_ws + BLOCKS * sizeof(float));

    int n = in_sizes[0];
    int n_vec = n / 4;  // N = 33554432, divisible by 4

    hipMemsetAsync(counter, 0, sizeof(unsigned int), stream);
    mse_fused_kernel<<<BLOCKS, THREADS, 0, stream>>>(pred, lab, partials, counter,
                                                     out, n_vec, 1.0f / (float)n);
}

// Round 4
// 47.070 us; speedup vs baseline: 2.4188x; 2.4188x over previous
//
#include <hip/hip_runtime.h>

// Thresholded MSE == plain MSE (all branches compute (x-y)^2).
// Two-pass deterministic reduction (fused last-block variant REGRESSED 2.3x:
// 2048 device-scope __threadfence ops trashed L2 residency — do not refuse).
//   K1: grid-stride float4 loads (simple loop: 12 VGPR, ~70% occupancy; the
//       x4-unroll variant was perf-neutral at lower occupancy) -> wave
//       shuffle reduce -> LDS cross-wave reduce -> partial per block in d_ws.
//   K2: one wave (64 threads) reduces 2048 partials, writes mean.

#define BLOCKS 2048
#define THREADS 256

__global__ __launch_bounds__(THREADS) void mse_partial_kernel(
    const float* __restrict__ pred, const float* __restrict__ lab,
    float* __restrict__ partials, int n_vec /* = N/4 */) {
    int tid = blockIdx.x * blockDim.x + threadIdx.x;
    int stride = gridDim.x * blockDim.x;

    const float4* p4 = reinterpret_cast<const float4*>(pred);
    const float4* l4 = reinterpret_cast<const float4*>(lab);

    float acc = 0.0f;
    for (int i = tid; i < n_vec; i += stride) {
        float4 p = p4[i];
        float4 l = l4[i];
        float d0 = p.x - l.x;
        float d1 = p.y - l.y;
        float d2 = p.z - l.z;
        float d3 = p.w - l.w;
        acc += d0 * d0 + d1 * d1 + d2 * d2 + d3 * d3;
    }

    // wave64 reduce
    #pragma unroll
    for (int off = 32; off > 0; off >>= 1)
        acc += __shfl_down(acc, off, 64);

    // cross-wave reduce via LDS (4 waves per 256-thread block)
    __shared__ float wsum[THREADS / 64];
    int lane = threadIdx.x & 63;
    int wave = threadIdx.x >> 6;
    if (lane == 0) wsum[wave] = acc;
    __syncthreads();
    if (threadIdx.x == 0) {
        partials[blockIdx.x] = wsum[0] + wsum[1] + wsum[2] + wsum[3];
    }
}

__global__ __launch_bounds__(64) void mse_final_kernel(
    const float* __restrict__ partials, float* __restrict__ out,
    float inv_n) {
    // one wave, no LDS, no __syncthreads
    const float4* p4 = reinterpret_cast<const float4*>(partials);
    float acc = 0.0f;
    #pragma unroll
    for (int j = 0; j < BLOCKS / 4 / 64; ++j) {  // 8 float4 per lane
        float4 v = p4[j * 64 + threadIdx.x];
        acc += (v.x + v.y) + (v.z + v.w);
    }
    #pragma unroll
    for (int off = 32; off > 0; off >>= 1)
        acc += __shfl_down(acc, off, 64);
    if (threadIdx.x == 0) out[0] = acc * inv_n;
}

extern "C" void kernel_launch(void* const* d_in, const int* in_sizes, int n_in,
                              void* d_out, int out_size, void* d_ws, size_t ws_size,
                              hipStream_t stream) {
    const float* pred = (const float*)d_in[0];
    const float* lab  = (const float*)d_in[1];
    float* out = (float*)d_out;
    float* partials = (float*)d_ws;  // BLOCKS floats (8 KB)

    int n = in_sizes[0];
    int n_vec = n / 4;  // N = 33554432, divisible by 4

    mse_partial_kernel<<<BLOCKS, THREADS, 0, stream>>>(pred, lab, partials, n_vec);
    mse_final_kernel<<<1, 64, 0, stream>>>(partials, out, 1.0f / (float)n);
}